// Round 5
// baseline (131.972 us; speedup 1.0000x reference)
//
#include <hip/hip_runtime.h>
#include <hip/hip_bf16.h>

typedef __bf16 bf16x8 __attribute__((ext_vector_type(8)));
typedef float  f32x4  __attribute__((ext_vector_type(4)));

#define NB 16
#define CI 128
#define CO 128
#define HH 64
#define WW 64

// slab: 4 halo rows x 66 halo cols x (32 ch + 8 pad) bf16, double buffered.
// stride 40 elems = 20 words; b128 4-word chunks at stride-20 tile banks cleanly.
#define SROWS 4
#define SCOLS 66
#define SSTR  40
#define QSZ   ((size_t)16 * 64 * 64 * 32)   // elems per ch-quarter of xT

// prep: blocks 0..1023 transpose+cvt x into xT (ch-innermost, 4 quarters);
//       1024..1095 swizzle w into A-frag order; 1096..1223 parity weight sums.
__global__ void prep(const float* __restrict__ x, __bf16* __restrict__ Ag,
                     float* __restrict__ wsum, __bf16* __restrict__ xT) {
    __shared__ float tile[128 * 65];          // 33280 B (red[] overlays tile)
    const int blk = blockIdx.x, tid = threadIdx.x;
    if (blk < 1024) {
        const int bb = blk >> 6, y = blk & 63;
        const float* xr = x + ((size_t)bb * CI) * (HH * WW) + y * WW;
        for (int idx = tid; idx < 2048; idx += 256) {   // 128 c x 16 float4
            int c = idx >> 4, x4 = idx & 15;
            float4 v = *(const float4*)(xr + (size_t)c * (HH * WW) + x4 * 4);
            *(float4*)(tile + c * 65 + x4 * 4) = v;
        }
        __syncthreads();
        for (int idx = tid; idx < 1024; idx += 256) {   // 64 px x 16 ch-chunks
            int px = idx >> 4, cg = idx & 15;
            bf16x8 o8;
            #pragma unroll
            for (int j = 0; j < 8; ++j)
                o8[j] = (__bf16)tile[(cg * 8 + j) * 65 + px];
            __bf16* dst = xT + (size_t)(cg >> 2) * QSZ
                        + (((size_t)bb * 64 + y) * 64 + px) * 32 + (cg & 3) * 8;
            *(bf16x8*)dst = o8;
        }
    } else if (blk < 1096) {
        int gid  = (blk - 1024) * 256 + tid;            // [0, 18432)
        int l    = gid & 63;
        int frag = gid >> 6;                            // t*8 + mt
        int mt   = frag & 7;
        int t    = frag >> 3;                           // [0, 36)
        int tap  = t >> 2;
        int r    = tap % 3;
        int s    = tap / 3;
        int o    = mt * 16 + (l & 15);
        int cb   = (t & 3) * 32 + (l >> 4) * 8;
        bf16x8 v;
        #pragma unroll
        for (int j = 0; j < 8; ++j)
            v[j] = (__bf16)x[0];                        // placeholder, overwritten below
        #pragma unroll
        for (int j = 0; j < 8; ++j) {
            // w element: w[o][cb+j][r][s]
            v[j] = (__bf16)((const float*)wsum == nullptr ? 0.f : 0.f);
        }
        // (real body below — see note)
        const float* w = (const float*)xT;              // unused; silence
        (void)w;
        // --- actual swizzle ---
        // NOTE: w pointer passed via x? No — w is a separate arg; restructured:
        *(bf16x8*)(Ag + (size_t)gid * 8) = v;
    }
    // wsum handled in prep2 below
}

// The above A-swizzle needs w; keep prep focused on x-transpose and do
// A-swizzle + wsum in prep_w (separate small kernel, 200 blocks).
__global__ void prep_w(const float* __restrict__ w, __bf16* __restrict__ Ag,
                       float* __restrict__ wsum) {
    __shared__ float red[8];
    const int blk = blockIdx.x, tid = threadIdx.x;
    if (blk < 72) {
        int gid  = blk * 256 + tid;
        int l    = gid & 63;
        int frag = gid >> 6;
        int mt   = frag & 7;
        int t    = frag >> 3;
        int tap  = t >> 2;
        int r    = tap % 3;
        int s    = tap / 3;
        int o    = mt * 16 + (l & 15);
        int cb   = (t & 3) * 32 + (l >> 4) * 8;
        bf16x8 v;
        #pragma unroll
        for (int j = 0; j < 8; ++j)
            v[j] = (__bf16)w[((o * CI + cb + j) * 3 + r) * 3 + s];
        *(bf16x8*)(Ag + (size_t)gid * 8) = v;
    } else {
        int o = blk - 72;
        const float* p = w + (size_t)o * CI * 9;
        float se = 0.f, so = 0.f;
        for (int idx = tid; idx < CI * 9; idx += 256) {
            int c = idx / 9;
            float v = p[idx];
            if (c & 1) so += v; else se += v;
        }
        #pragma unroll
        for (int off = 32; off; off >>= 1) {
            se += __shfl_down(se, off);
            so += __shfl_down(so, off);
        }
        int wave = tid >> 6, lane = tid & 63;
        if (lane == 0) { red[wave * 2] = se; red[wave * 2 + 1] = so; }
        __syncthreads();
        if (tid == 0) {
            wsum[o]      = red[0] + red[2] + red[4] + red[6];
            wsum[CO + o] = red[1] + red[3] + red[5] + red[7];
        }
    }
}

// One block = (batch, output row-pair): M=128 x N=128 x K=1152, 512 threads,
// wave tile 64x32. K split into 4 ch-quarters; slab double-buffered so quarter
// q+1's staging loads fly during quarter q's 9-tap MFMA loop. 4 barriers total.
__global__ __launch_bounds__(512, 4) void conv_main(
        const __bf16* __restrict__ xT,
        const float* __restrict__ bias,
        const float* __restrict__ wsum,
        const __bf16* __restrict__ Ag,
        float* __restrict__ out)
{
    __shared__ __align__(16) __bf16 slab[2][SROWS * SCOLS * SSTR]; // 42240 B
    __shared__ float Srow[SROWS * SCOLS * 2];                      //  2112 B
    __shared__ float avgl[256];                                    //  1024 B

    const int tid  = threadIdx.x;
    const int b    = blockIdx.y;
    const int row0 = blockIdx.x * 2;

    const int wave = tid >> 6, lane = tid & 63;
    const int wm = wave >> 2;                 // 0..1 : o-half
    const int wn = wave & 3;                  // (row, col-half)
    const int rsel = wn >> 1, csel = wn & 1;
    const int m = lane & 15, qv = lane >> 4;

    f32x4 acc[4][2];
    #pragma unroll
    for (int i = 0; i < 4; ++i)
        #pragma unroll
        for (int j = 0; j < 2; ++j)
            acc[i][j] = (f32x4){0.f, 0.f, 0.f, 0.f};

    int bbase[2];
    #pragma unroll
    for (int nt = 0; nt < 2; ++nt)
        bbase[nt] = (rsel * SCOLS + csel * 32 + nt * 16 + m) * SSTR + qv * 8;

    const __bf16* Abase = Ag + ((size_t)(wm * 4) << 9) + ((size_t)lane << 3);

    // ---- staging helpers: 1056 16B-chunks per quarter, <=3 per thread ----
    // chunk u: cg = u&3 (8-ch group), pc = u>>2 (r*66+col)
    bf16x8 sreg[3];
    auto stage_load = [&](int qq) {
        #pragma unroll
        for (int k = 0; k < 3; ++k) {
            int u  = tid + (k << 9);
            int uc = u < 1056 ? u : 1055;
            int cg = uc & 3, pc = uc >> 2;
            int col = pc % 66, r = pc / 66;
            int yi = row0 - 1 + r; yi = yi < 0 ? 0 : (yi > HH - 1 ? HH - 1 : yi);
            int xi = col - 1;      xi = xi < 0 ? 0 : (xi > WW - 1 ? WW - 1 : xi);
            sreg[k] = *(const bf16x8*)(xT + (size_t)qq * QSZ
                        + (((size_t)b * 64 + yi) * 64 + xi) * 32 + cg * 8);
        }
    };
    auto stage_write = [&](int buf) {
        #pragma unroll
        for (int k = 0; k < 3; ++k) {
            int u = tid + (k << 9);
            if (u < 1056) {
                int cg = u & 3, pc = u >> 2;
                *(bf16x8*)(&slab[buf][pc * SSTR + cg * 8]) = sreg[k];
            }
        }
    };

    // ---- prologue: A(t=0) prefetch + stage quarter 0 ----
    bf16x8 Acur[4];
    #pragma unroll
    for (int i = 0; i < 4; ++i)
        Acur[i] = *(const bf16x8*)(Abase + ((size_t)i << 9));
    stage_load(0);
    stage_write(0);
    __syncthreads();

    for (int qq = 0; qq < 4; ++qq) {
        const __bf16* sl = slab[qq & 1];
        #pragma unroll
        for (int tap = 0; tap < 9; ++tap) {
            // depth-1 A prefetch (next tap, or next quarter's tap 0)
            int tn = (tap < 8) ? ((tap + 1) * 4 + qq) : (qq < 3 ? qq + 1 : 35);
            bf16x8 Anx[4];
            #pragma unroll
            for (int i = 0; i < 4; ++i)
                Anx[i] = *(const bf16x8*)(Abase + ((size_t)(tn * 8 + i) << 9));
            if (tap == 0) {
                if (qq < 3) stage_load(qq + 1);   // fly during this quarter's MFMAs
                if (tid < SROWS * SCOLS) {        // Srow accumulate for quarter qq
                    const __bf16* p = sl + tid * SSTR;
                    float se = 0.f, so = 0.f;
                    #pragma unroll
                    for (int cg = 0; cg < 4; ++cg) {
                        bf16x8 v = *(const bf16x8*)(p + cg * 8);
                        se += (float)v[0] + (float)v[2] + (float)v[4] + (float)v[6];
                        so += (float)v[1] + (float)v[3] + (float)v[5] + (float)v[7];
                    }
                    if (qq == 0) { Srow[tid * 2] = se;  Srow[tid * 2 + 1] = so; }
                    else         { Srow[tid * 2] += se; Srow[tid * 2 + 1] += so; }
                }
            }
            const int s_ = tap >= 6 ? 2 : (tap >= 3 ? 1 : 0);
            const int r3 = tap - s_ * 3;
            const int boff = (s_ * SCOLS + r3) * SSTR;
            bf16x8 Bf[2];
            #pragma unroll
            for (int nt = 0; nt < 2; ++nt)
                Bf[nt] = *(const bf16x8*)(sl + bbase[nt] + boff);
            #pragma unroll
            for (int i = 0; i < 4; ++i)
                #pragma unroll
                for (int nt = 0; nt < 2; ++nt)
                    acc[i][nt] = __builtin_amdgcn_mfma_f32_16x16x32_bf16(
                        Acur[i], Bf[nt], acc[i][nt], 0, 0, 0);
            #pragma unroll
            for (int i = 0; i < 4; ++i)
                Acur[i] = Anx[i];
        }
        if (qq < 3) {
            stage_write((qq + 1) & 1);
            __syncthreads();
        }
    }

    __syncthreads();
    if (tid < 256) {                          // 3x3 box mean per (row, col, parity)
        int uu  = tid & 1;
        int col = (tid >> 1) & 63;
        int rr  = tid >> 7;
        float ssum = 0.f;
        #pragma unroll
        for (int dy = 0; dy < 3; ++dy)
            #pragma unroll
            for (int dx = 0; dx < 3; ++dx)
                ssum += Srow[(((rr + dy) * SCOLS) + (col + dx)) * 2 + uu];
        avgl[tid] = ssum * (1.0f / 576.0f);
    }
    __syncthreads();

    // ---- epilogue ----
    float a0v[2], a1v[2];
    #pragma unroll
    for (int nt = 0; nt < 2; ++nt) {
        int col = csel * 32 + nt * 16 + m;
        a0v[nt] = avgl[rsel * 128 + col * 2 + 0];
        a1v[nt] = avgl[rsel * 128 + col * 2 + 1];
    }
    float* outb = out + (size_t)b * CO * HH * WW + (size_t)(row0 + rsel) * WW
                      + csel * 32;
    #pragma unroll
    for (int i = 0; i < 4; ++i) {
        #pragma unroll
        for (int rg = 0; rg < 4; ++rg) {
            int o = wm * 64 + i * 16 + qv * 4 + rg;  // C/D row = (lane>>4)*4 + reg
            float bo = bias[o];
            float w0 = wsum[o];
            float w1 = wsum[CO + o];
            float* po = outb + (size_t)o * (HH * WW);
            #pragma unroll
            for (int nt = 0; nt < 2; ++nt) {
                float v = acc[i][nt][rg] + bo - a0v[nt] * w0 - a1v[nt] * w1;
                v = v > 0.f ? v : 0.01f * v;
                v += (o & 1) ? a1v[nt] : a0v[nt];
                __builtin_nontemporal_store(v, po + nt * 16 + m);
            }
        }
    }
}

extern "C" void kernel_launch(void* const* d_in, const int* in_sizes, int n_in,
                              void* d_out, int out_size, void* d_ws, size_t ws_size,
                              hipStream_t stream) {
    const float* x    = (const float*)d_in[0];
    const float* w    = (const float*)d_in[1];
    const float* bias = (const float*)d_in[2];
    float* out = (float*)d_out;

    __bf16* Ag   = (__bf16*)d_ws;                     // 294912 B
    float*  wsum = (float*)((char*)d_ws + 294912);    // 1024 B
    __bf16* xT   = (__bf16*)((char*)d_ws + 295936);   // 16 MB, 4 ch-quarters

    prep<<<1024, 256, 0, stream>>>(x, Ag, wsum, xT);  // x transpose only (blk<1024)
    prep_w<<<200, 256, 0, stream>>>(w, Ag, wsum);     // A swizzle + wsum

    dim3 grid(HH / 2, NB);                            // 512 blocks
    conv_main<<<grid, 512, 0, stream>>>(xT, bias, wsum, Ag, out);
}

// Round 6
// 113.078 us; speedup vs baseline: 1.1671x; 1.1671x over previous
//
#include <hip/hip_runtime.h>
#include <hip/hip_bf16.h>

typedef __bf16 bf16x8 __attribute__((ext_vector_type(8)));
typedef float  f32x4  __attribute__((ext_vector_type(4)));

#define NB 16
#define CI 128
#define CO 128
#define HH 64
#define WW 64

#define SCOLS 66
#define SPIX  (6 * SCOLS)                    // 396 halo pixels per slab
#define QSZ   ((size_t)NB * HH * WW * 32)    // elems per ch-quarter of xT

// async global->LDS, 16B per lane: lds dst = base + lane*16 (wave-uniform base)
#define GLDS16(gp, lp) __builtin_amdgcn_global_load_lds( \
    (const __attribute__((address_space(1))) unsigned int*)(const void*)(gp), \
    (__attribute__((address_space(3))) unsigned int*)(void*)(lp), 16, 0, 0)

// prep: blk<1024: transpose+cvt x -> xT (ch-innermost, 4 quarters) + per-pixel
// parity sums S (fp32). 1024..1095: w -> A-frag order. 1096..1223: wsum.
__global__ void prep(const float* __restrict__ x, const float* __restrict__ w,
                     __bf16* __restrict__ Ag, float* __restrict__ wsum,
                     __bf16* __restrict__ xT, float* __restrict__ S) {
    __shared__ float tile[128 * 65];          // 33280 B
    __shared__ float red[8];
    const int blk = blockIdx.x, tid = threadIdx.x;
    if (blk < 1024) {
        const int bb = blk >> 6, y = blk & 63;
        const float* xr = x + ((size_t)bb * CI) * (HH * WW) + y * WW;
        for (int idx = tid; idx < 2048; idx += 256) {   // 128 c x 16 float4
            int c = idx >> 4, x4 = idx & 15;
            float4 v = *(const float4*)(xr + (size_t)c * (HH * WW) + x4 * 4);
            *(float4*)(tile + c * 65 + x4 * 4) = v;
        }
        __syncthreads();
        for (int idx = tid; idx < 1024; idx += 256) {   // 64 px x 16 ch-chunks
            int px = idx >> 4, cg = idx & 15;
            bf16x8 o8;
            #pragma unroll
            for (int j = 0; j < 8; ++j)
                o8[j] = (__bf16)tile[(cg * 8 + j) * 65 + px];
            __bf16* dst = xT + (size_t)(cg >> 2) * QSZ
                        + (((size_t)bb * 64 + y) * 64 + px) * 32 + (cg & 3) * 8;
            *(bf16x8*)dst = o8;
        }
        if (tid < 64) {                                 // fp32 parity sums
            float se = 0.f, so = 0.f;
            #pragma unroll 8
            for (int c = 0; c < 128; c += 2) {
                se += tile[c * 65 + tid];
                so += tile[(c + 1) * 65 + tid];
            }
            float2 v = {se, so};
            *(float2*)(S + (((size_t)bb * 64 + y) * 64 + tid) * 2) = v;
        }
    } else if (blk < 1096) {
        int gid  = (blk - 1024) * 256 + tid;            // [0, 18432)
        int l    = gid & 63;
        int frag = gid >> 6;                            // t*8 + mt
        int mt   = frag & 7;
        int t    = frag >> 3;                           // [0, 36)
        int tap  = t >> 2;
        int r    = tap % 3;
        int s    = tap / 3;
        int o    = mt * 16 + (l & 15);
        int cb   = (t & 3) * 32 + (l >> 4) * 8;
        bf16x8 v;
        #pragma unroll
        for (int j = 0; j < 8; ++j)
            v[j] = (__bf16)w[((o * CI + cb + j) * 3 + r) * 3 + s];
        *(bf16x8*)(Ag + (size_t)gid * 8) = v;
    } else {
        int o = blk - 1096;
        const float* p = w + (size_t)o * CI * 9;
        float se = 0.f, so = 0.f;
        for (int idx = tid; idx < CI * 9; idx += 256) {
            int c = idx / 9;
            float v = p[idx];
            if (c & 1) so += v; else se += v;
        }
        #pragma unroll
        for (int off = 32; off; off >>= 1) {
            se += __shfl_down(se, off);
            so += __shfl_down(so, off);
        }
        int wv = tid >> 6, lane = tid & 63;
        if (lane == 0) { red[wv * 2] = se; red[wv * 2 + 1] = so; }
        __syncthreads();
        if (tid == 0) {
            wsum[o]      = red[0] + red[2] + red[4] + red[6];
            wsum[CO + o] = red[1] + red[3] + red[5] + red[7];
        }
    }
}

// One block = (batch, 4-row group): M=128 x N=256 x K=1152. 256 blocks = 1/CU.
// A staged in LDS (shared by 8 waves) -> K-loop is pure LDS+MFMA. A prefetch
// for quarter q+1 split across the two per-quarter barriers so every vmcnt(0)
// drain lands on loads issued >=4 taps (~1.5k cyc) earlier.
__global__ __launch_bounds__(512, 2) void conv_main(
        const __bf16* __restrict__ xT,
        const float* __restrict__ S,
        const float* __restrict__ bias,
        const float* __restrict__ wsum,
        const __bf16* __restrict__ Ag,
        float* __restrict__ out)
{
    __shared__ __align__(16) __bf16 Alds[9 * 4096];        // 73728 B
    __shared__ __align__(16) __bf16 slab[2][SPIX * 32];    // 50688 B
    __shared__ float SrowS[6 * 64 * 2];                    //  3072 B
    __shared__ float avgl[512];                            //  2048 B

    const int tid  = threadIdx.x;
    const int b    = blockIdx.y;
    const int row0 = blockIdx.x * 4;          // output rows row0..row0+3

    const int wave = tid >> 6, lane = tid & 63;
    const int wm = wave >> 2;                 // o-half
    const int wn = wave & 3;                  // output row within group
    const int m = lane & 15, qv = lane >> 4;

    // A chunks: 72 per quarter (tap 0..8 x part 0..7), 1KB each
    auto issue_A = [&](int qn, int a0, int a1) {
        for (int a = a0 + wave; a < a1; a += 8) {
            int tap = a >> 3, part = a & 7;
            const __bf16* gp = Ag
                + (((size_t)((tap * 4 + qn) * 8 + part)) << 9) + (lane << 3);
            GLDS16(gp, &Alds[(size_t)a << 9]);
        }
    };
    // slab chunks: 25 per quarter (16 pixels x 64B each)
    auto issue_slab = [&](int qn, __bf16* dst) {
        for (int c = wave; c < 25; c += 8) {
            int p   = c * 16 + (lane >> 2);
            int r   = (p * 993) >> 16;        // p/66 for p<512
            int col = p - r * 66;
            int yi  = row0 - 1 + r; yi = yi < 0 ? 0 : (yi > 63 ? 63 : yi);
            int xi  = col - 1;      xi = xi < 0 ? 0 : (xi > 63 ? 63 : xi);
            const __bf16* gp = xT + (size_t)qn * QSZ
                + (((size_t)b * 64 + yi) * 64 + xi) * 32 + (lane & 3) * 8;
            if (p < SPIX) GLDS16(gp, dst + ((size_t)c << 9));
        }
    };

    // ---- prologue: async-stage A[0] + slab[0]; gather S halo ----
    issue_slab(0, slab[0]);
    issue_A(0, 0, 72);
    for (int idx = tid; idx < 768; idx += 512) {    // 6 rows x 64 cols x 2 par
        int r = idx >> 7, rem = idx & 127;
        int col = rem >> 1, uu = idx & 1;
        int yi = row0 - 1 + r; yi = yi < 0 ? 0 : (yi > 63 ? 63 : yi);
        SrowS[idx] = S[(((size_t)b * 64 + yi) * 64 + col) * 2 + uu];
    }
    __syncthreads();
    {   // 3x3 clamped box mean per (out-row, col, parity)
        int rr = tid >> 7, col = (tid >> 1) & 63, uu = tid & 1;
        float ssum = 0.f;
        #pragma unroll
        for (int dy = 0; dy < 3; ++dy)
            #pragma unroll
            for (int dx = 0; dx < 3; ++dx) {
                int cc = col - 1 + dx; cc = cc < 0 ? 0 : (cc > 63 ? 63 : cc);
                ssum += SrowS[((rr + dy) * 64 + cc) * 2 + uu];
            }
        avgl[tid] = ssum * (1.0f / 576.0f);
    }

    f32x4 acc[4][4];
    #pragma unroll
    for (int i = 0; i < 4; ++i)
        #pragma unroll
        for (int j = 0; j < 4; ++j)
            acc[i][j] = (f32x4){0.f, 0.f, 0.f, 0.f};

    int bbase[4];
    #pragma unroll
    for (int nt = 0; nt < 4; ++nt)
        bbase[nt] = (wn * SCOLS + nt * 16 + m) * 32 + qv * 8;
    const __bf16* Aw = Alds + (wm * 4) * 512 + lane * 8;

    for (int q = 0; q < 4; ++q) {
        const __bf16* sl = slab[q & 1];
        if (q < 3) issue_slab(q + 1, slab[(q + 1) & 1]);
        #pragma unroll
        for (int tap = 0; tap < 4; ++tap) {
            const int s_ = tap / 3, r3 = tap % 3;
            const int poff = (s_ * SCOLS + r3) * 32;
            bf16x8 Bf[4], Af[4];
            #pragma unroll
            for (int nt = 0; nt < 4; ++nt)
                Bf[nt] = *(const bf16x8*)(sl + bbase[nt] + poff);
            #pragma unroll
            for (int i = 0; i < 4; ++i)
                Af[i] = *(const bf16x8*)(Aw + (tap * 8 + i) * 512);
            #pragma unroll
            for (int i = 0; i < 4; ++i)
                #pragma unroll
                for (int nt = 0; nt < 4; ++nt)
                    acc[i][nt] = __builtin_amdgcn_mfma_f32_16x16x32_bf16(
                        Af[i], Bf[nt], acc[i][nt], 0, 0, 0);
        }
        __syncthreads();                      // all waves done A taps 0-3
        if (q < 3) issue_A(q + 1, 0, 32);
        #pragma unroll
        for (int tap = 4; tap < 9; ++tap) {
            const int s_ = tap / 3, r3 = tap % 3;
            const int poff = (s_ * SCOLS + r3) * 32;
            bf16x8 Bf[4], Af[4];
            #pragma unroll
            for (int nt = 0; nt < 4; ++nt)
                Bf[nt] = *(const bf16x8*)(sl + bbase[nt] + poff);
            #pragma unroll
            for (int i = 0; i < 4; ++i)
                Af[i] = *(const bf16x8*)(Aw + (tap * 8 + i) * 512);
            #pragma unroll
            for (int i = 0; i < 4; ++i)
                #pragma unroll
                for (int nt = 0; nt < 4; ++nt)
                    acc[i][nt] = __builtin_amdgcn_mfma_f32_16x16x32_bf16(
                        Af[i], Bf[nt], acc[i][nt], 0, 0, 0);
        }
        __syncthreads();                      // all waves done A taps 4-8 + slab
        if (q < 3) issue_A(q + 1, 32, 72);
    }

    // ---- epilogue ----
    float a0v[4], a1v[4];
    #pragma unroll
    for (int nt = 0; nt < 4; ++nt) {
        int col = nt * 16 + m;
        a0v[nt] = avgl[wn * 128 + col * 2 + 0];
        a1v[nt] = avgl[wn * 128 + col * 2 + 1];
    }
    float* outb = out + (size_t)b * CO * HH * WW + (size_t)(row0 + wn) * WW;
    #pragma unroll
    for (int i = 0; i < 4; ++i) {
        #pragma unroll
        for (int rg = 0; rg < 4; ++rg) {
            int o = wm * 64 + i * 16 + qv * 4 + rg;  // C/D row = (lane>>4)*4+reg
            float bo = bias[o];
            float w0 = wsum[o];
            float w1 = wsum[CO + o];
            float* po = outb + (size_t)o * (HH * WW);
            #pragma unroll
            for (int nt = 0; nt < 4; ++nt) {
                float v = acc[i][nt][rg] + bo - a0v[nt] * w0 - a1v[nt] * w1;
                v = v > 0.f ? v : 0.01f * v;
                v += (o & 1) ? a1v[nt] : a0v[nt];
                __builtin_nontemporal_store(v, po + nt * 16 + m);
            }
        }
    }
}

extern "C" void kernel_launch(void* const* d_in, const int* in_sizes, int n_in,
                              void* d_out, int out_size, void* d_ws, size_t ws_size,
                              hipStream_t stream) {
    const float* x    = (const float*)d_in[0];
    const float* w    = (const float*)d_in[1];
    const float* bias = (const float*)d_in[2];
    float* out = (float*)d_out;

    __bf16* Ag   = (__bf16*)d_ws;                     // 294912 B, frag-order w
    float*  wsum = (float*)((char*)d_ws + 294912);    // 1024 B
    __bf16* xT   = (__bf16*)((char*)d_ws + 295936);   // 16 MB, 4 ch-quarters
    float*  S    = (float*)((char*)d_ws + 295936 + 2 * QSZ * 4);  // 512 KB

    prep<<<1224, 256, 0, stream>>>(x, w, Ag, wsum, xT, S);

    dim3 grid(HH / 4, NB);                            // 16 row-groups x 16 b
    conv_main<<<grid, 512, 0, stream>>>(xT, S, bias, wsum, Ag, out);
}